// Round 2
// baseline (76.099 us; speedup 1.0000x reference)
//
#include <hip/hip_runtime.h>

// TreeGCN fused kernels for MI355X (gfx950) — R1.
// B=64, NODES=512, DEG=8, IN_F=64, OUT_F=64, SUP=640.
// Algebraic opt: WsF = Ws1@Ws2 precomputed (no nonlinearity between).
// R1: block=(node,deg) -> 4096 blocks, 2 barriers/block, direct-global
// MFMA fragments for WsF^T / W3^T, LDS 18.4KB (Bt + Ts only).

typedef float f32x4 __attribute__((ext_vector_type(4)));
typedef __bf16 bf16x8 __attribute__((ext_vector_type(8)));

__device__ __forceinline__ unsigned short f2bf(float f) {
    union { float f; unsigned int u; } x; x.f = f;
    unsigned int r = x.u + 0x7FFFu + ((x.u >> 16) & 1u);
    return (unsigned short)(r >> 16);
}

#define LDP 72  // bf16 row stride: 144 B -> even 8-way bank spread for b128 reads

// ---------------- prep: ylow + WsF^T bf16 + W3^T bf16 ------------------------
// grid 1089 x 256
__global__ __launch_bounds__(256) void tree_prep(
    const float* __restrict__ x0, const float* __restrict__ W0,
    const float* __restrict__ x1, const float* __restrict__ W1,
    const float* __restrict__ x2, const float* __restrict__ W2,
    const float* __restrict__ Ws1, const float* __restrict__ Ws2,
    const float* __restrict__ W3,
    float* __restrict__ ylow, unsigned short* __restrict__ wsW,
    unsigned short* __restrict__ w3t)
{
    const int t = threadIdx.x;
    const int blk = blockIdx.x;
    if (blk < 1024) {
        // ylow[b][g][f] = (x0@W0)[b,f] + (x1@W1)[b,g>>3,f] + (x2@W2)[b,g,f]
        const int b = blk >> 4;
        const int g = ((blk & 15) << 2) + (t >> 6);
        const int f = t & 63;
        float acc = 0.f;
        const float* xp = x0 + b * 96;
        #pragma unroll 4
        for (int k = 0; k < 96; ++k) acc += xp[k] * W0[k * 64 + f];
        const float* x1p = x1 + b * 512 + (g >> 3) * 64;
        #pragma unroll 4
        for (int k = 0; k < 64; ++k) acc += x1p[k] * W1[k * 64 + f];
        const float* x2p = x2 + b * 4096 + g * 64;
        #pragma unroll 4
        for (int k = 0; k < 64; ++k) acc += x2p[k] * W2[k * 64 + f];
        ylow[b * 4096 + g * 64 + f] = acc;
    } else if (blk < 1088) {
        // wsW[f][c] = (Ws1@Ws2)[c][f] bf16 ; block = one c row, s split 4-way
        __shared__ float red[4][64];
        const int c = blk - 1024;
        const int f = t & 63, q = t >> 6;
        const float* w1p = Ws1 + (size_t)c * 640 + q * 160;
        const float* w2p = Ws2 + (size_t)(q * 160) * 64 + f;
        float acc = 0.f;
        #pragma unroll 4
        for (int s = 0; s < 160; ++s) acc += w1p[s] * w2p[(size_t)s * 64];
        red[q][f] = acc;
        __syncthreads();
        if (q == 0)
            wsW[f * 64 + c] = f2bf(red[0][f] + red[1][f] + red[2][f] + red[3][f]);
    } else {
        // w3t[f][k] = bf16(W3[k][f])
        #pragma unroll
        for (int i = 0; i < 16; ++i) {
            const int e = i * 256 + t;
            const int f = e >> 6, k = e & 63;
            w3t[e] = f2bf(W3[k * 64 + f]);
        }
    }
}

// ---------------- main: one (node, deg) per block ----------------------------
__global__ __launch_bounds__(256, 4) void tree_main(
    const float* __restrict__ x3, const float* __restrict__ branch,
    const float* __restrict__ bias, const float* __restrict__ ylow,
    const unsigned short* __restrict__ wsW, const unsigned short* __restrict__ w3t,
    float* __restrict__ out)
{
    __shared__ unsigned short Bt[64 * LDP];  // bf16 branch-slice^T [c][k]
    __shared__ unsigned short Ts[64 * LDP];  // bf16 T [b][c] (wave-private rows)

    const int t = threadIdx.x;
    const int l = t & 63;
    const int w = t >> 6;
    const int blk = blockIdx.x;
    const int n = blk >> 3, d = blk & 7;
    const int l15 = l & 15;
    const int l4 = l >> 4;
    const int rk = t & 15;   // transpose-stage: k-quad
    const int rc = t >> 4;   // transpose-stage: c-quad

    // ---- issue branch-slice loads (16 floats/thread)
    const float* brn = branch + (size_t)n * 32768 + d * 64;
    float4 bl[4];
    #pragma unroll
    for (int i = 0; i < 4; ++i)
        bl[i] = *(const float4*)(brn + (size_t)(4 * rk + i) * 512 + 4 * rc);

    // ---- A-fragments of X directly from global x3 (row b=16w+l15)
    const int brow = 16 * w + l15;
    const float* xr = x3 + (size_t)brow * 32768 + (size_t)n * 64;
    bf16x8 af[2];
    #pragma unroll
    for (int ks = 0; ks < 2; ++ks) {
        float4 u = *(const float4*)(xr + 32 * ks + 8 * l4);
        float4 v = *(const float4*)(xr + 32 * ks + 8 * l4 + 4);
        union { unsigned short h[8]; bf16x8 bv; } p;
        p.h[0] = f2bf(u.x); p.h[1] = f2bf(u.y); p.h[2] = f2bf(u.z); p.h[3] = f2bf(u.w);
        p.h[4] = f2bf(v.x); p.h[5] = f2bf(v.y); p.h[6] = f2bf(v.z); p.h[7] = f2bf(v.w);
        af[ks] = p.bv;
    }

    // ---- write Bt = bf16(branch slice)^T [c][k]
    #pragma unroll
    for (int ci = 0; ci < 4; ++ci) {
        union { unsigned short h[4]; uint2 u; } qq;
        #pragma unroll
        for (int i = 0; i < 4; ++i) qq.h[i] = f2bf(((const float*)&bl[i])[ci]);
        *(uint2*)&Bt[(4 * rc + ci) * LDP + 4 * rk] = qq.u;
    }

    // ---- Y = X@W3 + ylow (registers; b-frags direct from global w3t)
    f32x4 y[4];
    #pragma unroll
    for (int ft = 0; ft < 4; ++ft) {
        bf16x8 b0 = *(const bf16x8*)(w3t + (16 * ft + l15) * 64 + 8 * l4);
        bf16x8 b1 = *(const bf16x8*)(w3t + (16 * ft + l15) * 64 + 32 + 8 * l4);
        f32x4 acc = {0.f, 0.f, 0.f, 0.f};
        acc = __builtin_amdgcn_mfma_f32_16x16x32_bf16(af[0], b0, acc, 0, 0, 0);
        acc = __builtin_amdgcn_mfma_f32_16x16x32_bf16(af[1], b1, acc, 0, 0, 0);
        y[ft] = acc;
    }
    {
        const float* yl = ylow + (size_t)(n >> 3) * 64;
        #pragma unroll
        for (int ft = 0; ft < 4; ++ft)
            #pragma unroll
            for (int r = 0; r < 4; ++r)
                y[ft][r] += yl[(size_t)(16 * w + 4 * l4 + r) * 4096 + 16 * ft + l15];
    }
    __syncthreads();

    // ---- GEMM1: S = X @ Br_d
    f32x4 s[4];
    #pragma unroll
    for (int ct = 0; ct < 4; ++ct) {
        bf16x8 b0 = *(const bf16x8*)&Bt[(16 * ct + l15) * LDP + l4 * 8];
        bf16x8 b1 = *(const bf16x8*)&Bt[(16 * ct + l15) * LDP + 32 + l4 * 8];
        f32x4 acc = {0.f, 0.f, 0.f, 0.f};
        acc = __builtin_amdgcn_mfma_f32_16x16x32_bf16(af[0], b0, acc, 0, 0, 0);
        acc = __builtin_amdgcn_mfma_f32_16x16x32_bf16(af[1], b1, acc, 0, 0, 0);
        s[ct] = acc;
    }
    // lrelu -> bf16 -> Ts[b][c]
    #pragma unroll
    for (int ct = 0; ct < 4; ++ct)
        #pragma unroll
        for (int r = 0; r < 4; ++r) {
            float v = s[ct][r];
            v = fmaxf(v, 0.2f * v);
            Ts[(16 * w + 4 * l4 + r) * LDP + 16 * ct + l15] = f2bf(v);
        }
    __syncthreads();

    // ---- GEMM2: O = T @ WsF (b-frags direct from global wsW) ; epilogue
    bf16x8 at0 = *(const bf16x8*)&Ts[(16 * w + l15) * LDP + l4 * 8];
    bf16x8 at1 = *(const bf16x8*)&Ts[(16 * w + l15) * LDP + 32 + l4 * 8];
    #pragma unroll
    for (int ft = 0; ft < 4; ++ft) {
        bf16x8 wf0 = *(const bf16x8*)(wsW + (16 * ft + l15) * 64 + 8 * l4);
        bf16x8 wf1 = *(const bf16x8*)(wsW + (16 * ft + l15) * 64 + 32 + 8 * l4);
        f32x4 o = {0.f, 0.f, 0.f, 0.f};
        o = __builtin_amdgcn_mfma_f32_16x16x32_bf16(at0, wf0, o, 0, 0, 0);
        o = __builtin_amdgcn_mfma_f32_16x16x32_bf16(at1, wf1, o, 0, 0, 0);
        const float bv = bias[d * 64 + 16 * ft + l15];
        #pragma unroll
        for (int r = 0; r < 4; ++r) {
            float val = o[r] + y[ft][r] + bv;
            val = fmaxf(val, 0.2f * val);
            out[(size_t)(16 * w + 4 * l4 + r) * 262144 + (size_t)(n * 8 + d) * 64 + 16 * ft + l15] = val;
        }
    }
}

extern "C" void kernel_launch(void* const* d_in, const int* in_sizes, int n_in,
                              void* d_out, int out_size, void* d_ws, size_t ws_size,
                              hipStream_t stream) {
    (void)in_sizes; (void)n_in; (void)out_size; (void)ws_size;
    const float* x0     = (const float*)d_in[0];
    const float* W0     = (const float*)d_in[1];
    const float* x1     = (const float*)d_in[2];
    const float* W1     = (const float*)d_in[3];
    const float* x2     = (const float*)d_in[4];
    const float* W2     = (const float*)d_in[5];
    const float* x3     = (const float*)d_in[6];
    const float* W3     = (const float*)d_in[7];
    const float* branch = (const float*)d_in[8];
    const float* Ws1    = (const float*)d_in[9];
    const float* Ws2    = (const float*)d_in[10];
    const float* bias   = (const float*)d_in[11];

    float* ylow = (float*)d_ws;                                              // 1 MiB fp32
    unsigned short* wsW = (unsigned short*)((char*)d_ws + (size_t)1048576);  // 8 KiB bf16
    unsigned short* w3t = (unsigned short*)((char*)d_ws + (size_t)1048576 + 8192);
    float* out = (float*)d_out;

    tree_prep<<<1089, 256, 0, stream>>>(x0, W0, x1, W1, x2, W2, Ws1, Ws2, W3,
                                        ylow, wsW, w3t);
    tree_main<<<4096, 256, 0, stream>>>(x3, branch, bias, ylow, wsW, w3t, out);
}

// Round 3
// 62.703 us; speedup vs baseline: 1.2137x; 1.2137x over previous
//
#include <hip/hip_runtime.h>

// TreeGCN fused kernels for MI355X (gfx950) — R2.
// B=64, NODES=512, DEG=8, IN_F=64, OUT_F=64, SUP=640.
// Algebraic opt: WsF = Ws1@Ws2 precomputed (no nonlinearity between).
// R2: barrier-free main — one wave per (node, deg), wave-private LDS,
// all d-invariant work (Y = x3@W3 + ylow-replicate) precomputed in prep,
// x3 / WsF / Y stored PRE-FRAGMENTED so main fragment loads are single
// coalesced dwordx4's.

typedef float f32x4 __attribute__((ext_vector_type(4)));
typedef __bf16 bf16x8 __attribute__((ext_vector_type(8)));

__device__ __forceinline__ unsigned short f2bf(float f) {
    union { float f; unsigned int u; } x; x.f = f;
    unsigned int r = x.u + 0x7FFFu + ((x.u >> 16) & 1u);
    return (unsigned short)(r >> 16);
}

#define LDP 72  // bf16 row stride (144 B): 16B-aligned rows, benign conflicts

// ---------------- prep: Y (fp32) + xbf frags + WsF frags ---------------------
// grid 576 x 256: blocks 0..511 = (b, nblk); 512..575 = WsF rows
__global__ __launch_bounds__(256) void tree_prep(
    const float* __restrict__ x0, const float* __restrict__ W0,
    const float* __restrict__ x1, const float* __restrict__ W1,
    const float* __restrict__ x2, const float* __restrict__ W2,
    const float* __restrict__ x3, const float* __restrict__ W3,
    const float* __restrict__ Ws1, const float* __restrict__ Ws2,
    float* __restrict__ Yf, unsigned short* __restrict__ xbf,
    unsigned short* __restrict__ wsF)
{
    const int t = threadIdx.x;
    const int blk = blockIdx.x;
    if (blk < 512) {
        __shared__ unsigned short w3s[64 * LDP];  // W3^T bf16 [f][k]
        __shared__ float lvl[8][64];              // x2@W2 for this block's 8 g's
        __shared__ float lvl01[64];               // x0@W0 + x1@W1 (h = nblk)
        const int b = blk >> 3, nblk = blk & 7;

        // stage W3^T bf16
        {
            const int f = t >> 2, kq = t & 3;
            union { unsigned short h[8]; uint4 u; } p0, p1;
            #pragma unroll
            for (int i = 0; i < 8; ++i) {
                p0.h[i] = f2bf(W3[(kq * 16 + i) * 64 + f]);
                p1.h[i] = f2bf(W3[(kq * 16 + 8 + i) * 64 + f]);
            }
            *(uint4*)&w3s[f * LDP + kq * 16] = p0.u;
            *(uint4*)&w3s[f * LDP + kq * 16 + 8] = p1.u;
        }
        // lvl01[f] = (x0@W0)[b,f] + (x1@W1)[b,nblk,f]
        if (t < 64) {
            float a = 0.f;
            const float* x0p = x0 + b * 96;
            #pragma unroll 4
            for (int k = 0; k < 96; ++k) a += x0p[k] * W0[k * 64 + t];
            const float* x1p = x1 + b * 512 + nblk * 64;
            #pragma unroll 4
            for (int k = 0; k < 64; ++k) a += x1p[k] * W1[k * 64 + t];
            lvl01[t] = a;
        }
        // lvl[g][f] = (x2@W2)[b, nblk*8+g, f]
        #pragma unroll
        for (int j = 0; j < 2; ++j) {
            const int idx = t + 256 * j;
            const int g = idx >> 6, f = idx & 63;
            const float* x2p = x2 + (size_t)b * 4096 + (nblk * 8 + g) * 64;
            float a = 0.f;
            #pragma unroll 4
            for (int k = 0; k < 64; ++k) a += x2p[k] * W2[k * 64 + f];
            lvl[g][f] = a;
        }
        // xbf: pre-fragmented bf16 of x3 (A-operand frags per node)
        {
            const int np = t >> 2, kq = t & 3;
            const int n = nblk * 64 + np;
            const float* src = x3 + (size_t)b * 32768 + (size_t)n * 64 + kq * 16;
            float tmp[16];
            #pragma unroll
            for (int i = 0; i < 4; ++i) {
                float4 v = *(const float4*)(src + 4 * i);
                tmp[4*i+0] = v.x; tmp[4*i+1] = v.y; tmp[4*i+2] = v.z; tmp[4*i+3] = v.w;
            }
            const int mt = b >> 4, l15b = b & 15;
            #pragma unroll
            for (int h = 0; h < 2; ++h) {
                const int k0 = kq * 16 + 8 * h;
                const int ks = k0 >> 5, l4k = (k0 >> 3) & 3;
                union { unsigned short hh[8]; uint4 u; } p;
                #pragma unroll
                for (int j = 0; j < 8; ++j) p.hh[j] = f2bf(tmp[8 * h + j]);
                *(uint4*)&xbf[(size_t)n * 4096 +
                              (size_t)((mt * 2 + ks) * 64 + l4k * 16 + l15b) * 8] = p.u;
            }
        }
        __syncthreads();
        // Y = x3@W3 + lvl + lvl01, stored pre-fragmented fp32
        {
            const int w = t >> 6, l = t & 63;
            const int l15 = l & 15, l4 = l >> 4;
            bf16x8 af[2];
            #pragma unroll
            for (int ks = 0; ks < 2; ++ks) {
                const float* xr = x3 + (size_t)b * 32768 +
                                  (size_t)(nblk * 64 + 16 * w + l15) * 64 + 32 * ks + 8 * l4;
                float4 u = *(const float4*)(xr);
                float4 v = *(const float4*)(xr + 4);
                union { unsigned short h[8]; bf16x8 bv; } p;
                p.h[0]=f2bf(u.x); p.h[1]=f2bf(u.y); p.h[2]=f2bf(u.z); p.h[3]=f2bf(u.w);
                p.h[4]=f2bf(v.x); p.h[5]=f2bf(v.y); p.h[6]=f2bf(v.z); p.h[7]=f2bf(v.w);
                af[ks] = p.bv;
            }
            #pragma unroll
            for (int ft = 0; ft < 4; ++ft) {
                bf16x8 b0 = *(const bf16x8*)&w3s[(16 * ft + l15) * LDP + 8 * l4];
                bf16x8 b1 = *(const bf16x8*)&w3s[(16 * ft + l15) * LDP + 32 + 8 * l4];
                f32x4 acc = {0.f, 0.f, 0.f, 0.f};
                acc = __builtin_amdgcn_mfma_f32_16x16x32_bf16(af[0], b0, acc, 0, 0, 0);
                acc = __builtin_amdgcn_mfma_f32_16x16x32_bf16(af[1], b1, acc, 0, 0, 0);
                #pragma unroll
                for (int r = 0; r < 4; ++r) {
                    const int nr = 16 * w + 4 * l4 + r;
                    const int n = nblk * 64 + nr;
                    const float val = acc[r] + lvl[nr >> 3][16 * ft + l15] + lvl01[16 * ft + l15];
                    // frag layout: Yf[((n*4+mtb)*4+ft)*256 + (l4m*16+l15)*4 + rm]
                    Yf[(size_t)(((n * 4 + (b >> 4)) * 4 + ft)) * 256 +
                       (((b >> 2) & 3) * 16 + l15) * 4 + (b & 3)] = val;
                }
            }
        }
    } else {
        // WsF = (Ws1@Ws2) as pre-fragmented bf16 B-operand (rows f, k=c contig)
        __shared__ float red[4][64];
        const int c = blk - 512;
        const int f = t & 63, q = t >> 6;
        const float* w1p = Ws1 + (size_t)c * 640 + q * 160;
        const float* w2p = Ws2 + (size_t)(q * 160) * 64 + f;
        float acc = 0.f;
        #pragma unroll 4
        for (int s = 0; s < 160; ++s) acc += w1p[s] * w2p[(size_t)s * 64];
        red[q][f] = acc;
        __syncthreads();
        if (q == 0) {
            const float v = red[0][f] + red[1][f] + red[2][f] + red[3][f];
            const int ks = c >> 5, l4c = (c >> 3) & 3, j = c & 7;
            wsF[((f >> 4) * 2 + ks) * 512 + (l4c * 16 + (f & 15)) * 8 + j] = f2bf(v);
        }
    }
}

// ---------------- main: one wave per (node, deg), barrier-free ---------------
// grid 1024 x 256: n = blk>>1, d = (blk&1)*4 + wave
__global__ __launch_bounds__(256, 3) void tree_main(
    const float* __restrict__ branch, const float* __restrict__ bias,
    const float* __restrict__ Yf, const unsigned short* __restrict__ xbf,
    const unsigned short* __restrict__ wsF, float* __restrict__ out)
{
    __shared__ unsigned short buf[4][64 * LDP];  // per-wave Bt (reused as Ts)
    const int t = threadIdx.x;
    const int w = t >> 6, l = t & 63;
    const int l15 = l & 15, l4 = l >> 4;
    const int n = blockIdx.x >> 1;
    const int d = (blockIdx.x & 1) * 4 + w;
    unsigned short* bp = buf[w];

    const int rk = l & 15, cq = l >> 4;
    const float* brp = branch + (size_t)n * 32768 + d * 64;

    // issue all 16 branch-slice loads (64 regs, freed after transpose)
    float4 bl[4][4];
    #pragma unroll
    for (int jc = 0; jc < 4; ++jc)
        #pragma unroll
        for (int i = 0; i < 4; ++i)
            bl[jc][i] = *(const float4*)(brp + (size_t)(4 * rk + i) * 512 + 16 * jc + 4 * cq);

    // A-frags: single coalesced dwordx4 each (pre-fragmented, L3-hot)
    bf16x8 af[4][2];
    #pragma unroll
    for (int mt = 0; mt < 4; ++mt)
        #pragma unroll
        for (int ks = 0; ks < 2; ++ks)
            af[mt][ks] = *(const bf16x8*)(xbf + (size_t)n * 4096 +
                                          (size_t)((mt * 2 + ks) * 64 + l) * 8);

    // transpose-write Bt[c][k] (wave-private; DS in-order per wave)
    #pragma unroll
    for (int jc = 0; jc < 4; ++jc)
        #pragma unroll
        for (int ci = 0; ci < 4; ++ci) {
            union { unsigned short h[4]; uint2 u; } q;
            #pragma unroll
            for (int i = 0; i < 4; ++i) q.h[i] = f2bf(((const float*)&bl[jc][i])[ci]);
            *(uint2*)&bp[(16 * jc + 4 * cq + ci) * LDP + 4 * rk] = q.u;
        }

    // GEMM1: S = X @ Br_d  (4 m-tiles x 4 c-tiles)
    bf16x8 btf[4][2];
    #pragma unroll
    for (int ct = 0; ct < 4; ++ct) {
        btf[ct][0] = *(const bf16x8*)&bp[(16 * ct + l15) * LDP + 8 * l4];
        btf[ct][1] = *(const bf16x8*)&bp[(16 * ct + l15) * LDP + 32 + 8 * l4];
    }
    f32x4 s[4][4];
    #pragma unroll
    for (int mt = 0; mt < 4; ++mt)
        #pragma unroll
        for (int ct = 0; ct < 4; ++ct) {
            f32x4 acc = {0.f, 0.f, 0.f, 0.f};
            acc = __builtin_amdgcn_mfma_f32_16x16x32_bf16(af[mt][0], btf[ct][0], acc, 0, 0, 0);
            acc = __builtin_amdgcn_mfma_f32_16x16x32_bf16(af[mt][1], btf[ct][1], acc, 0, 0, 0);
            s[mt][ct] = acc;
        }

    // lrelu -> bf16 -> Ts[b][c] (overwrites Bt; all btf reads already consumed)
    #pragma unroll
    for (int mt = 0; mt < 4; ++mt)
        #pragma unroll
        for (int ct = 0; ct < 4; ++ct)
            #pragma unroll
            for (int r = 0; r < 4; ++r) {
                float v = s[mt][ct][r];
                v = fmaxf(v, 0.2f * v);
                bp[(16 * mt + 4 * l4 + r) * LDP + 16 * ct + l15] = f2bf(v);
            }

    // B-frags of WsF (tiny, L1/L2-hot)
    bf16x8 wf[4][2];
    #pragma unroll
    for (int ft = 0; ft < 4; ++ft)
        #pragma unroll
        for (int ks = 0; ks < 2; ++ks)
            wf[ft][ks] = *(const bf16x8*)(wsF + (size_t)((ft * 2 + ks) * 64 + l) * 8);

    // GEMM2 + epilogue (Y frag loads coalesced dwordx4, L3-hot)
    #pragma unroll
    for (int mt = 0; mt < 4; ++mt) {
        bf16x8 at0 = *(const bf16x8*)&bp[(16 * mt + l15) * LDP + 8 * l4];
        bf16x8 at1 = *(const bf16x8*)&bp[(16 * mt + l15) * LDP + 32 + 8 * l4];
        #pragma unroll
        for (int ft = 0; ft < 4; ++ft) {
            f32x4 o = {0.f, 0.f, 0.f, 0.f};
            o = __builtin_amdgcn_mfma_f32_16x16x32_bf16(at0, wf[ft][0], o, 0, 0, 0);
            o = __builtin_amdgcn_mfma_f32_16x16x32_bf16(at1, wf[ft][1], o, 0, 0, 0);
            const f32x4 yv = *(const f32x4*)(Yf + (size_t)(((n * 4 + mt) * 4 + ft)) * 256 + l * 4);
            const float bv = bias[d * 64 + 16 * ft + l15];
            #pragma unroll
            for (int r = 0; r < 4; ++r) {
                float val = o[r] + yv[r] + bv;
                val = fmaxf(val, 0.2f * val);
                out[(size_t)(16 * mt + 4 * l4 + r) * 262144 +
                    (size_t)(n * 8 + d) * 64 + 16 * ft + l15] = val;
            }
        }
    }
}

extern "C" void kernel_launch(void* const* d_in, const int* in_sizes, int n_in,
                              void* d_out, int out_size, void* d_ws, size_t ws_size,
                              hipStream_t stream) {
    (void)in_sizes; (void)n_in; (void)out_size; (void)ws_size;
    const float* x0     = (const float*)d_in[0];
    const float* W0     = (const float*)d_in[1];
    const float* x1     = (const float*)d_in[2];
    const float* W1     = (const float*)d_in[3];
    const float* x2     = (const float*)d_in[4];
    const float* W2     = (const float*)d_in[5];
    const float* x3     = (const float*)d_in[6];
    const float* W3     = (const float*)d_in[7];
    const float* branch = (const float*)d_in[8];
    const float* Ws1    = (const float*)d_in[9];
    const float* Ws2    = (const float*)d_in[10];
    const float* bias   = (const float*)d_in[11];

    float* Yf          = (float*)d_ws;                                   // 8 MiB fp32 frags
    unsigned short* xbf = (unsigned short*)((char*)d_ws + 8388608);      // 4 MiB bf16 frags
    unsigned short* wsF = (unsigned short*)((char*)d_ws + 12582912);     // 8 KiB bf16 frags
    float* out = (float*)d_out;

    tree_prep<<<576, 256, 0, stream>>>(x0, W0, x1, W1, x2, W2, x3, W3, Ws1, Ws2,
                                       Yf, xbf, wsF);
    tree_main<<<1024, 256, 0, stream>>>(branch, bias, Yf, xbf, wsF, out);
}

// Round 4
// 54.370 us; speedup vs baseline: 1.3996x; 1.1532x over previous
//
#include <hip/hip_runtime.h>

// TreeGCN fused kernels for MI355X (gfx950) — R3.
// B=64, NODES=512, DEG=8, IN_F=64, OUT_F=64, SUP=640.
// WsF = Ws1@Ws2 precomputed (no nonlinearity between).
// R3: one-wave blocks (64t), max per-wave MLP, direct-global B-frags,
// in-wave Y (ylg frag table as MFMA C-init), tiny thread-parallel prep.

typedef float f32x4 __attribute__((ext_vector_type(4)));
typedef __bf16 bf16x8 __attribute__((ext_vector_type(8)));

__device__ __forceinline__ unsigned short f2bf(float f) {
    union { float f; unsigned int u; } x; x.f = f;
    unsigned int r = x.u + 0x7FFFu + ((x.u >> 16) & 1u);
    return (unsigned short)(r >> 16);
}

// ---------------- prep: ylg frags + xbf frags + wsF frags + w3f frags --------
// grid 3137 x 256: [0,1024) ylg; [1024,3072) xbf; [3072,3136) wsF; 3136 w3f
__global__ __launch_bounds__(256) void tree_prep(
    const float* __restrict__ x0, const float* __restrict__ W0,
    const float* __restrict__ x1, const float* __restrict__ W1,
    const float* __restrict__ x2, const float* __restrict__ W2,
    const float* __restrict__ x3, const float* __restrict__ W3,
    const float* __restrict__ Ws1, const float* __restrict__ Ws2,
    float* __restrict__ ylg, unsigned short* __restrict__ xbf,
    unsigned short* __restrict__ wsF, unsigned short* __restrict__ w3f)
{
    const int t = threadIdx.x;
    const int blk = blockIdx.x;
    if (blk < 1024) {
        // ylg[b][g][f] = (x0@W0)[b,f] + (x1@W1)[b,g>>3,f] + (x2@W2)[b,g,f]
        // stored in MFMA C-frag layout keyed by g.
        const int b = blk >> 4;
        const int g = ((blk & 15) << 2) + (t >> 6);
        const int f = t & 63;
        const float* xp = x0 + b * 96;
        float a0 = 0.f, a1 = 0.f;
        #pragma unroll 8
        for (int k = 0; k < 96; k += 2) {
            a0 += xp[k]     * W0[k * 64 + f];
            a1 += xp[k + 1] * W0[(k + 1) * 64 + f];
        }
        const float* x1p = x1 + b * 512 + (g >> 3) * 64;
        #pragma unroll 8
        for (int k = 0; k < 64; k += 2) {
            a0 += x1p[k]     * W1[k * 64 + f];
            a1 += x1p[k + 1] * W1[(k + 1) * 64 + f];
        }
        const float* x2p = x2 + b * 4096 + g * 64;
        #pragma unroll 8
        for (int k = 0; k < 64; k += 2) {
            a0 += x2p[k]     * W2[k * 64 + f];
            a1 += x2p[k + 1] * W2[(k + 1) * 64 + f];
        }
        const int mt = b >> 4, l4 = (b >> 2) & 3, r = b & 3;
        const int ft = f >> 4, l15 = f & 15;
        ylg[(size_t)((g * 4 + mt) * 4 + ft) * 256 + (l4 * 16 + l15) * 4 + r] = a0 + a1;
    } else if (blk < 3072) {
        // xbf: bf16 A-operand frags of x3, keyed by n
        const int bb = blk - 1024;
        const int b = bb >> 5, ngrp = bb & 31;
        const int n = ngrp * 16 + (t >> 4), k0 = 4 * (t & 15);
        float4 v = *(const float4*)(x3 + (size_t)b * 32768 + (size_t)n * 64 + k0);
        const int mt = b >> 4, l15b = b & 15, ks = k0 >> 5, l4k = (k0 >> 3) & 3, j = k0 & 7;
        union { unsigned short h[4]; uint2 u; } p;
        p.h[0] = f2bf(v.x); p.h[1] = f2bf(v.y); p.h[2] = f2bf(v.z); p.h[3] = f2bf(v.w);
        *(uint2*)&xbf[(size_t)n * 4096 + ((mt * 2 + ks) * 64 + l4k * 16 + l15b) * 8 + j] = p.u;
    } else if (blk < 3136) {
        // wsF B-frags: value WsF[c][f] = (Ws1@Ws2)[c][f]; block = one c
        __shared__ float red[4][64];
        const int c = blk - 3072;
        const int f = t & 63, q = t >> 6;
        const float* w1p = Ws1 + (size_t)c * 640 + q * 160;
        const float* w2p = Ws2 + (size_t)(q * 160) * 64 + f;
        float a0 = 0.f, a1 = 0.f;
        #pragma unroll 8
        for (int s = 0; s < 160; s += 2) {
            a0 += w1p[s]     * w2p[(size_t)s * 64];
            a1 += w1p[s + 1] * w2p[(size_t)(s + 1) * 64];
        }
        red[q][f] = a0 + a1;
        __syncthreads();
        if (q == 0) {
            const float v = red[0][f] + red[1][f] + red[2][f] + red[3][f];
            const int ks = c >> 5, l4c = (c >> 3) & 3, j = c & 7;
            wsF[((f >> 4) * 2 + ks) * 512 + (l4c * 16 + (f & 15)) * 8 + j] = f2bf(v);
        }
    } else {
        // w3f B-frags: value W3[k][f]
        const int l = t & 63;
        #pragma unroll
        for (int it = 0; it < 2; ++it) {
            const int fh = it * 4 + (t >> 6);        // (ft*2+ks), 0..7
            const int ft = fh >> 1, ks = fh & 1;
            const int f = ft * 16 + (l & 15);
            const int kb = ks * 32 + (l >> 4) * 8;
            union { unsigned short h[8]; uint4 u; } p;
            #pragma unroll
            for (int j = 0; j < 8; ++j) p.h[j] = f2bf(W3[(kb + j) * 64 + f]);
            *(uint4*)&w3f[((size_t)fh * 64 + l) * 8] = p.u;
        }
    }
}

// ---------------- main: one wave per (node, deg) -----------------------------
// grid 4096 x 64: n = blk>>3, d = blk&7
__global__ __launch_bounds__(64, 2) void tree_main(
    const float* __restrict__ branch, const float* __restrict__ bias,
    const float* __restrict__ ylg, const unsigned short* __restrict__ xbf,
    const unsigned short* __restrict__ wsF, const unsigned short* __restrict__ w3f,
    float* __restrict__ out)
{
    __shared__ unsigned short Ts[64 * 72];  // bf16 T [b][c], stride 72
    const int l = threadIdx.x;
    const int l15 = l & 15, l4 = l >> 4;
    const int n = blockIdx.x >> 3, d = blockIdx.x & 7;
    const int g = n >> 3;

    // ---- 1. issue branch B-frag element loads (64 dwords, 4x64B segs each)
    const float* bp = branch + (size_t)n * 32768 + d * 64 + l15;
    float br[4][2][8];
    #pragma unroll
    for (int ct = 0; ct < 4; ++ct)
        #pragma unroll
        for (int ks = 0; ks < 2; ++ks)
            #pragma unroll
            for (int j = 0; j < 8; ++j)
                br[ct][ks][j] = bp[(size_t)(ks * 32 + 8 * l4 + j) * 512 + 16 * ct];

    // ---- 2. A-frags of X (coalesced dwordx4, L3-hot)
    bf16x8 af[4][2];
    #pragma unroll
    for (int mt = 0; mt < 4; ++mt)
        #pragma unroll
        for (int ks = 0; ks < 2; ++ks)
            af[mt][ks] = *(const bf16x8*)(xbf + (size_t)n * 4096 +
                                          ((mt * 2 + ks) * 64 + l) * 8);

    // ---- 3. W3^T frags (tiny, L1-hot)
    bf16x8 w3[4][2];
    #pragma unroll
    for (int ft = 0; ft < 4; ++ft)
        #pragma unroll
        for (int ks = 0; ks < 2; ++ks)
            w3[ft][ks] = *(const bf16x8*)(w3f + (size_t)((ft * 2 + ks) * 64 + l) * 8);

    // ---- 4. y = ylg (C-init) + x3@W3
    f32x4 y[4][4];
    #pragma unroll
    for (int mt = 0; mt < 4; ++mt)
        #pragma unroll
        for (int ft = 0; ft < 4; ++ft)
            y[mt][ft] = *(const f32x4*)(ylg + (size_t)((g * 4 + mt) * 4 + ft) * 256 + l * 4);
    #pragma unroll
    for (int mt = 0; mt < 4; ++mt)
        #pragma unroll
        for (int ft = 0; ft < 4; ++ft) {
            y[mt][ft] = __builtin_amdgcn_mfma_f32_16x16x32_bf16(af[mt][0], w3[ft][0], y[mt][ft], 0, 0, 0);
            y[mt][ft] = __builtin_amdgcn_mfma_f32_16x16x32_bf16(af[mt][1], w3[ft][1], y[mt][ft], 0, 0, 0);
        }

    // ---- 5. GEMM1: S = X @ Br_d ; lrelu -> bf16 -> Ts
    #pragma unroll
    for (int ct = 0; ct < 4; ++ct) {
        union { unsigned short h[8]; bf16x8 bv; } p0, p1;
        #pragma unroll
        for (int j = 0; j < 8; ++j) { p0.h[j] = f2bf(br[ct][0][j]); p1.h[j] = f2bf(br[ct][1][j]); }
        #pragma unroll
        for (int mt = 0; mt < 4; ++mt) {
            f32x4 s = {0.f, 0.f, 0.f, 0.f};
            s = __builtin_amdgcn_mfma_f32_16x16x32_bf16(af[mt][0], p0.bv, s, 0, 0, 0);
            s = __builtin_amdgcn_mfma_f32_16x16x32_bf16(af[mt][1], p1.bv, s, 0, 0, 0);
            #pragma unroll
            for (int r = 0; r < 4; ++r) {
                float v = s[r];
                v = fmaxf(v, 0.2f * v);
                Ts[(16 * mt + 4 * l4 + r) * 72 + 16 * ct + l15] = f2bf(v);
            }
        }
    }

    // ---- 6. WsF B-frags (tiny, L1-hot)
    bf16x8 wf[4][2];
    #pragma unroll
    for (int ft = 0; ft < 4; ++ft)
        #pragma unroll
        for (int ks = 0; ks < 2; ++ks)
            wf[ft][ks] = *(const bf16x8*)(wsF + (size_t)((ft * 2 + ks) * 64 + l) * 8);

    // ---- 7. GEMM2 + epilogue
    float* outp = out + (size_t)blockIdx.x * 64;
    #pragma unroll
    for (int mt = 0; mt < 4; ++mt) {
        bf16x8 at0 = *(const bf16x8*)&Ts[(16 * mt + l15) * 72 + 8 * l4];
        bf16x8 at1 = *(const bf16x8*)&Ts[(16 * mt + l15) * 72 + 32 + 8 * l4];
        #pragma unroll
        for (int ft = 0; ft < 4; ++ft) {
            f32x4 o = {0.f, 0.f, 0.f, 0.f};
            o = __builtin_amdgcn_mfma_f32_16x16x32_bf16(at0, wf[ft][0], o, 0, 0, 0);
            o = __builtin_amdgcn_mfma_f32_16x16x32_bf16(at1, wf[ft][1], o, 0, 0, 0);
            const float bv = bias[d * 64 + 16 * ft + l15];
            #pragma unroll
            for (int r = 0; r < 4; ++r) {
                float val = o[r] + y[mt][ft][r] + bv;
                val = fmaxf(val, 0.2f * val);
                outp[(size_t)(16 * mt + 4 * l4 + r) * 262144 + 16 * ft + l15] = val;
            }
        }
    }
}

extern "C" void kernel_launch(void* const* d_in, const int* in_sizes, int n_in,
                              void* d_out, int out_size, void* d_ws, size_t ws_size,
                              hipStream_t stream) {
    (void)in_sizes; (void)n_in; (void)out_size; (void)ws_size;
    const float* x0     = (const float*)d_in[0];
    const float* W0     = (const float*)d_in[1];
    const float* x1     = (const float*)d_in[2];
    const float* W1     = (const float*)d_in[3];
    const float* x2     = (const float*)d_in[4];
    const float* W2     = (const float*)d_in[5];
    const float* x3     = (const float*)d_in[6];
    const float* W3     = (const float*)d_in[7];
    const float* branch = (const float*)d_in[8];
    const float* Ws1    = (const float*)d_in[9];
    const float* Ws2    = (const float*)d_in[10];
    const float* bias   = (const float*)d_in[11];

    float* ylg          = (float*)d_ws;                                   // 1 MiB
    unsigned short* xbf = (unsigned short*)((char*)d_ws + 1048576);       // 4 MiB
    unsigned short* wsF = (unsigned short*)((char*)d_ws + 5242880);       // 8 KiB
    unsigned short* w3f = (unsigned short*)((char*)d_ws + 5251072);       // 8 KiB
    float* out = (float*)d_out;

    tree_prep<<<3137, 256, 0, stream>>>(x0, W0, x1, W1, x2, W2, x3, W3, Ws1, Ws2,
                                        ylg, xbf, wsF, w3f);
    tree_main<<<4096, 64, 0, stream>>>(branch, bias, ylg, xbf, wsF, w3f, out);
}

// Round 5
// 54.036 us; speedup vs baseline: 1.4083x; 1.0062x over previous
//
#include <hip/hip_runtime.h>

// TreeGCN fused kernels for MI355X (gfx950) — R4.
// B=64, NODES=512, DEG=8, IN_F=64, OUT_F=64, SUP=640.
// WsF = Ws1@Ws2 precomputed (no nonlinearity between).
// R4: one-wave blocks; register diet (GEMM2 folded into y C-init chain,
// per-mt processing); branch staged via coalesced float4 + 2.25KB in-place
// reused LDS transpose, ct-pipelined; LDS 11.5KB/wave -> ~13 blocks/CU.

typedef float f32x4 __attribute__((ext_vector_type(4)));
typedef __bf16 bf16x8 __attribute__((ext_vector_type(8)));

__device__ __forceinline__ unsigned short f2bf(float f) {
    union { float f; unsigned int u; } x; x.f = f;
    unsigned int r = x.u + 0x7FFFu + ((x.u >> 16) & 1u);
    return (unsigned short)(r >> 16);
}

// ---------------- prep: ylg frags + xbf frags + wsF frags + w3f frags --------
// grid 3137 x 256: [0,1024) ylg; [1024,3072) xbf; [3072,3136) wsF; 3136 w3f
__global__ __launch_bounds__(256) void tree_prep(
    const float* __restrict__ x0, const float* __restrict__ W0,
    const float* __restrict__ x1, const float* __restrict__ W1,
    const float* __restrict__ x2, const float* __restrict__ W2,
    const float* __restrict__ x3, const float* __restrict__ W3,
    const float* __restrict__ Ws1, const float* __restrict__ Ws2,
    float* __restrict__ ylg, unsigned short* __restrict__ xbf,
    unsigned short* __restrict__ wsF, unsigned short* __restrict__ w3f)
{
    const int t = threadIdx.x;
    const int blk = blockIdx.x;
    if (blk < 1024) {
        const int b = blk >> 4;
        const int g = ((blk & 15) << 2) + (t >> 6);
        const int f = t & 63;
        const float* xp = x0 + b * 96;
        float a0 = 0.f, a1 = 0.f;
        #pragma unroll 8
        for (int k = 0; k < 96; k += 2) {
            a0 += xp[k]     * W0[k * 64 + f];
            a1 += xp[k + 1] * W0[(k + 1) * 64 + f];
        }
        const float* x1p = x1 + b * 512 + (g >> 3) * 64;
        #pragma unroll 8
        for (int k = 0; k < 64; k += 2) {
            a0 += x1p[k]     * W1[k * 64 + f];
            a1 += x1p[k + 1] * W1[(k + 1) * 64 + f];
        }
        const float* x2p = x2 + b * 4096 + g * 64;
        #pragma unroll 8
        for (int k = 0; k < 64; k += 2) {
            a0 += x2p[k]     * W2[k * 64 + f];
            a1 += x2p[k + 1] * W2[(k + 1) * 64 + f];
        }
        const int mt = b >> 4, l4 = (b >> 2) & 3, r = b & 3;
        const int ft = f >> 4, l15 = f & 15;
        ylg[(size_t)((g * 4 + mt) * 4 + ft) * 256 + (l4 * 16 + l15) * 4 + r] = a0 + a1;
    } else if (blk < 3072) {
        const int bb = blk - 1024;
        const int b = bb >> 5, ngrp = bb & 31;
        const int n = ngrp * 16 + (t >> 4), k0 = 4 * (t & 15);
        float4 v = *(const float4*)(x3 + (size_t)b * 32768 + (size_t)n * 64 + k0);
        const int mt = b >> 4, l15b = b & 15, ks = k0 >> 5, l4k = (k0 >> 3) & 3, j = k0 & 7;
        union { unsigned short h[4]; uint2 u; } p;
        p.h[0] = f2bf(v.x); p.h[1] = f2bf(v.y); p.h[2] = f2bf(v.z); p.h[3] = f2bf(v.w);
        *(uint2*)&xbf[(size_t)n * 4096 + ((mt * 2 + ks) * 64 + l4k * 16 + l15b) * 8 + j] = p.u;
    } else if (blk < 3136) {
        __shared__ float red[4][64];
        const int c = blk - 3072;
        const int f = t & 63, q = t >> 6;
        const float* w1p = Ws1 + (size_t)c * 640 + q * 160;
        const float* w2p = Ws2 + (size_t)(q * 160) * 64 + f;
        float a0 = 0.f, a1 = 0.f;
        #pragma unroll 8
        for (int s = 0; s < 160; s += 2) {
            a0 += w1p[s]     * w2p[(size_t)s * 64];
            a1 += w1p[s + 1] * w2p[(size_t)(s + 1) * 64];
        }
        red[q][f] = a0 + a1;
        __syncthreads();
        if (q == 0) {
            const float v = red[0][f] + red[1][f] + red[2][f] + red[3][f];
            const int ks = c >> 5, l4c = (c >> 3) & 3, j = c & 7;
            wsF[((f >> 4) * 2 + ks) * 512 + (l4c * 16 + (f & 15)) * 8 + j] = f2bf(v);
        }
    } else {
        const int l = t & 63;
        #pragma unroll
        for (int it = 0; it < 2; ++it) {
            const int fh = it * 4 + (t >> 6);
            const int ft = fh >> 1, ks = fh & 1;
            const int f = ft * 16 + (l & 15);
            const int kb = ks * 32 + (l >> 4) * 8;
            union { unsigned short h[8]; uint4 u; } p;
            #pragma unroll
            for (int j = 0; j < 8; ++j) p.h[j] = f2bf(W3[(kb + j) * 64 + f]);
            *(uint4*)&w3f[((size_t)fh * 64 + l) * 8] = p.u;
        }
    }
}

// ---------------- main: one wave per (node, deg) -----------------------------
// grid 4096 x 64: n = blk>>3, d = blk&7
__global__ __launch_bounds__(64, 3) void tree_main(
    const float* __restrict__ branch, const float* __restrict__ bias,
    const float* __restrict__ ylg, const unsigned short* __restrict__ xbf,
    const unsigned short* __restrict__ wsF, const unsigned short* __restrict__ w3f,
    float* __restrict__ out)
{
    __shared__ unsigned short Bt[16 * 72];  // one ct's branch^T slice, reused in place
    __shared__ unsigned short Ts[64 * 72];  // bf16 T [b][c]
    const int l = threadIdx.x;
    const int l15 = l & 15, l4 = l >> 4;
    const int n = blockIdx.x >> 3, d = blockIdx.x & 7;
    const int g = n >> 3;
    const int rk = l & 15, cq = l >> 4;

    const float* brp = branch + (size_t)n * 32768 + d * 64 + 4 * cq;

    // issue ct=0 branch loads (coalesced float4: 1KB/instr)
    float4 bl[4];
    #pragma unroll
    for (int i = 0; i < 4; ++i)
        bl[i] = *(const float4*)(brp + (size_t)(4 * rk + i) * 512);

    // A-frags of X (coalesced dwordx4, L2/L3-hot; resident both phases)
    bf16x8 af[4][2];
    #pragma unroll
    for (int mt = 0; mt < 4; ++mt)
        #pragma unroll
        for (int ks = 0; ks < 2; ++ks)
            af[mt][ks] = *(const bf16x8*)(xbf + (size_t)n * 4096 +
                                          ((mt * 2 + ks) * 64 + l) * 8);

    // ---- GEMM1, pipelined over ct: S = X @ Br_d ; lrelu -> bf16 -> Ts
    #pragma unroll
    for (int ct = 0; ct < 4; ++ct) {
        // transpose-write Bt[c-local][k] for this ct
        #pragma unroll
        for (int ci = 0; ci < 4; ++ci) {
            union { unsigned short h[4]; uint2 u; } q;
            #pragma unroll
            for (int i = 0; i < 4; ++i) q.h[i] = f2bf(((const float*)&bl[i])[ci]);
            *(uint2*)&Bt[(4 * cq + ci) * 72 + 4 * rk] = q.u;
        }
        // prefetch next ct's branch columns
        if (ct < 3) {
            #pragma unroll
            for (int i = 0; i < 4; ++i)
                bl[i] = *(const float4*)(brp + (size_t)(4 * rk + i) * 512 + 16 * (ct + 1));
        }
        // B-frags (wave-private LDS, in-order DS pipe: no barrier needed)
        bf16x8 bt0 = *(const bf16x8*)&Bt[l15 * 72 + 8 * l4];
        bf16x8 bt1 = *(const bf16x8*)&Bt[l15 * 72 + 32 + 8 * l4];
        #pragma unroll
        for (int mt = 0; mt < 4; ++mt) {
            f32x4 s = {0.f, 0.f, 0.f, 0.f};
            s = __builtin_amdgcn_mfma_f32_16x16x32_bf16(af[mt][0], bt0, s, 0, 0, 0);
            s = __builtin_amdgcn_mfma_f32_16x16x32_bf16(af[mt][1], bt1, s, 0, 0, 0);
            #pragma unroll
            for (int r = 0; r < 4; ++r) {
                float v = s[r];
                v = fmaxf(v, 0.2f * v);
                Ts[(16 * mt + 4 * l4 + r) * 72 + 16 * ct + l15] = f2bf(v);
            }
        }
    }

    // ---- phase 2 constants (loaded after GEMM1 to cut peak regs; L1-hot)
    bf16x8 w3[4][2], wf[4][2];
    #pragma unroll
    for (int ft = 0; ft < 4; ++ft)
        #pragma unroll
        for (int ks = 0; ks < 2; ++ks) {
            w3[ft][ks] = *(const bf16x8*)(w3f + (size_t)((ft * 2 + ks) * 64 + l) * 8);
            wf[ft][ks] = *(const bf16x8*)(wsF + (size_t)((ft * 2 + ks) * 64 + l) * 8);
        }
    float bv[4];
    #pragma unroll
    for (int ft = 0; ft < 4; ++ft) bv[ft] = bias[d * 64 + 16 * ft + l15];

    // ---- per-mt: y = ylg + x3@W3 + T@WsF ; epilogue
    float* outp = out + (size_t)blockIdx.x * 64;
    #pragma unroll
    for (int mt = 0; mt < 4; ++mt) {
        f32x4 y[4];
        #pragma unroll
        for (int ft = 0; ft < 4; ++ft)
            y[ft] = *(const f32x4*)(ylg + (size_t)((g * 4 + mt) * 4 + ft) * 256 + l * 4);
        bf16x8 at0 = *(const bf16x8*)&Ts[(16 * mt + l15) * 72 + 8 * l4];
        bf16x8 at1 = *(const bf16x8*)&Ts[(16 * mt + l15) * 72 + 32 + 8 * l4];
        #pragma unroll
        for (int ft = 0; ft < 4; ++ft) {
            y[ft] = __builtin_amdgcn_mfma_f32_16x16x32_bf16(af[mt][0], w3[ft][0], y[ft], 0, 0, 0);
            y[ft] = __builtin_amdgcn_mfma_f32_16x16x32_bf16(af[mt][1], w3[ft][1], y[ft], 0, 0, 0);
            y[ft] = __builtin_amdgcn_mfma_f32_16x16x32_bf16(at0, wf[ft][0], y[ft], 0, 0, 0);
            y[ft] = __builtin_amdgcn_mfma_f32_16x16x32_bf16(at1, wf[ft][1], y[ft], 0, 0, 0);
        }
        #pragma unroll
        for (int ft = 0; ft < 4; ++ft)
            #pragma unroll
            for (int r = 0; r < 4; ++r) {
                float val = y[ft][r] + bv[ft];
                val = fmaxf(val, 0.2f * val);
                outp[(size_t)(16 * mt + 4 * l4 + r) * 262144 + 16 * ft + l15] = val;
            }
    }
}

extern "C" void kernel_launch(void* const* d_in, const int* in_sizes, int n_in,
                              void* d_out, int out_size, void* d_ws, size_t ws_size,
                              hipStream_t stream) {
    (void)in_sizes; (void)n_in; (void)out_size; (void)ws_size;
    const float* x0     = (const float*)d_in[0];
    const float* W0     = (const float*)d_in[1];
    const float* x1     = (const float*)d_in[2];
    const float* W1     = (const float*)d_in[3];
    const float* x2     = (const float*)d_in[4];
    const float* W2     = (const float*)d_in[5];
    const float* x3     = (const float*)d_in[6];
    const float* W3     = (const float*)d_in[7];
    const float* branch = (const float*)d_in[8];
    const float* Ws1    = (const float*)d_in[9];
    const float* Ws2    = (const float*)d_in[10];
    const float* bias   = (const float*)d_in[11];

    float* ylg          = (float*)d_ws;                                   // 1 MiB
    unsigned short* xbf = (unsigned short*)((char*)d_ws + 1048576);       // 4 MiB
    unsigned short* wsF = (unsigned short*)((char*)d_ws + 5242880);       // 8 KiB
    unsigned short* w3f = (unsigned short*)((char*)d_ws + 5251072);       // 8 KiB
    float* out = (float*)d_out;

    tree_prep<<<3137, 256, 0, stream>>>(x0, W0, x1, W1, x2, W2, x3, W3, Ws1, Ws2,
                                        ylg, xbf, wsF, w3f);
    tree_main<<<4096, 64, 0, stream>>>(branch, bias, ylg, xbf, wsF, w3f, out);
}